// Round 1
// baseline (914.206 us; speedup 1.0000x reference)
//
#include <hip/hip_runtime.h>
#include <math.h>

#define A_NUM 1024
#define L_NUM 16384
#define NANG  121
#define KSPLIT 16
#define ATILES 16
#define TA 64
#define LCH (L_NUM / KSPLIT)   // 1024 l per block
#define LC 32                  // l chunk staged in LDS

// ws layout (f32 offsets)
#define WS_TV   0                       // theta_vec [16384][2]
#define WS_WF   32768                   // w_full [121][1024][2]
#define WS_B    280576                  // B [1024][121][2]
#define WS_SOUT 528384                  // sout [121][121]
#define WS_PART 543744                  // partials [16][1024][121][2]
#define PART_STRIDE 247808

// ---------------- K1: prep theta_vec + w_full ----------------
__global__ __launch_bounds__(256) void k_prep(
    const float* __restrict__ w_re, const float* __restrict__ w_im,
    const float* __restrict__ th_re, const float* __restrict__ th_im,
    float* __restrict__ ws)
{
    int idx = blockIdx.x * 256 + threadIdx.x;
    if (idx < 16384) {
        // theta_vec: 4-fold mirrored [128][128] of normalized ts[64][64]
        int i = idx >> 7, j = idx & 127;
        int r = (i < 64) ? i : 127 - i;
        int c = (j < 64) ? j : 127 - j;
        float tr = th_re[r * 64 + c], ti = th_im[r * 64 + c];
        float inv = rsqrtf(tr * tr + ti * ti);
        ws[WS_TV + 2 * idx]     = tr * inv;
        ws[WS_TV + 2 * idx + 1] = ti * inv;
    } else if (idx < 16384 + 121 * 1024) {
        // w_full: rows 0..60 = wn; rows 61..120: w_full[r][a] = wn[120-r][1023-a]
        int e = idx - 16384;
        int r = e >> 10, a = e & 1023;
        int sr = (r < 61) ? r : 120 - r;
        int sa = (r < 61) ? a : 1023 - a;
        float wr = w_re[sr * 1024 + sa], wi = w_im[sr * 1024 + sa];
        float mag = sqrtf(wr * wr + wi * wi);
        float s = (mag > 1.0f) ? (1.0f / mag) : 1.0f;
        ws[WS_WF + 2 * e]     = wr * s;
        ws[WS_WF + 2 * e + 1] = wi * s;
    }
}

// ---------------- K2: B_partial = (G .* theta) @ sv ----------------
// block: 256 thr = 16 tn x 16 ta ; per-thread tile 4a x 8n (4 n-pairs)
// grid: (ATILES=16 a-tiles of 64) x (KSPLIT=16 chunks of 1024 l)
__global__ __launch_bounds__(256) void k_gemm1(
    const float* __restrict__ G_re, const float* __restrict__ G_im,
    const float* __restrict__ sv_re, const float* __restrict__ sv_im,
    float* __restrict__ ws)
{
    __shared__ __align__(16) float lgt[TA * 66];   // [a][33 pairs] stride 66 (conflict-free)
    __shared__ __align__(16) float lsv[LC * 256];  // [l][128 n-pairs interleaved re,im]
    const int t  = threadIdx.x;
    const int a0 = blockIdx.x * TA;
    const int lb0 = blockIdx.y * LCH;
    const float* __restrict__ tv = ws + WS_TV;
    const int tn = t & 15, ta = t >> 4;

    float accr[4][8], acci[4][8];
    #pragma unroll
    for (int j = 0; j < 4; j++)
        #pragma unroll
        for (int h = 0; h < 8; h++) { accr[j][h] = 0.0f; acci[j][h] = 0.0f; }

    for (int lc = 0; lc < LCH; lc += LC) {
        const int lbase = lb0 + lc;
        // stage Gt = G * theta : 64a x 32l complex
        #pragma unroll
        for (int k = 0; k < 8; k++) {
            int e = t + k * 256;
            int a = e >> 5, l = e & 31;
            size_t gi_idx = (size_t)(a0 + a) * L_NUM + lbase + l;
            float gr = G_re[gi_idx];
            float gim = G_im[gi_idx];
            float tr = tv[2 * (lbase + l)], ti = tv[2 * (lbase + l) + 1];
            lgt[a * 66 + 2 * l]     = gr * tr - gim * ti;
            lgt[a * 66 + 2 * l + 1] = gr * ti + gim * tr;
        }
        // stage sv : 32l x 128n (pad n>=121 with 0)
        #pragma unroll
        for (int k = 0; k < 16; k++) {
            int e = t + k * 256;
            int l = e >> 7, n = e & 127;
            float svr = 0.0f, svi = 0.0f;
            if (n < NANG) {
                size_t si = (size_t)(lbase + l) * NANG + n;
                svr = sv_re[si]; svi = sv_im[si];
            }
            lsv[l * 256 + 2 * n]     = svr;
            lsv[l * 256 + 2 * n + 1] = svi;
        }
        __syncthreads();
        #pragma unroll 8
        for (int l = 0; l < LC; l++) {
            float2 g[4];
            #pragma unroll
            for (int j = 0; j < 4; j++)
                g[j] = *(const float2*)&lgt[(4 * ta + j) * 66 + 2 * l];
            float4 s[4];
            #pragma unroll
            for (int gg = 0; gg < 4; gg++)
                s[gg] = *(const float4*)&lsv[l * 256 + 4 * tn + 64 * gg];
            #pragma unroll
            for (int j = 0; j < 4; j++) {
                #pragma unroll
                for (int gg = 0; gg < 4; gg++) {
                    float4 s4 = s[gg];
                    accr[j][2 * gg]     += g[j].x * s4.x - g[j].y * s4.y;
                    acci[j][2 * gg]     += g[j].x * s4.y + g[j].y * s4.x;
                    accr[j][2 * gg + 1] += g[j].x * s4.z - g[j].y * s4.w;
                    acci[j][2 * gg + 1] += g[j].x * s4.w + g[j].y * s4.z;
                }
            }
        }
        __syncthreads();
    }
    // write this k-chunk's partial
    float* part = ws + WS_PART + (size_t)blockIdx.y * PART_STRIDE;
    #pragma unroll
    for (int j = 0; j < 4; j++) {
        int a = a0 + 4 * ta + j;
        #pragma unroll
        for (int gg = 0; gg < 4; gg++) {
            #pragma unroll
            for (int h = 0; h < 2; h++) {
                int n = 2 * tn + 32 * gg + h;
                if (n < NANG) {
                    part[((size_t)a * NANG + n) * 2]     = accr[j][2 * gg + h];
                    part[((size_t)a * NANG + n) * 2 + 1] = acci[j][2 * gg + h];
                }
            }
        }
    }
}

// ---------------- K2b: B = sum of KSPLIT partials ----------------
__global__ __launch_bounds__(256) void k_reduce_part(float* __restrict__ ws)
{
    int e = blockIdx.x * 256 + threadIdx.x;  // < 247808
    const float* part = ws + WS_PART;
    float s = 0.0f;
    #pragma unroll
    for (int p = 0; p < KSPLIT; p++) s += part[(size_t)p * PART_STRIDE + e];
    ws[WS_B + e] = s;
}

// ---------------- K3: sout = |w_full @ B|^2 / (A*L) ----------------
__global__ __launch_bounds__(128) void k_gemm2(float* __restrict__ ws)
{
    __shared__ __align__(16) float lw[2048];
    const int r = blockIdx.x;
    const int t = threadIdx.x;
    const float* __restrict__ wf = ws + WS_WF + r * 2048;
    #pragma unroll
    for (int k = 0; k < 16; k++) lw[t + k * 128] = wf[t + k * 128];
    __syncthreads();
    if (t < NANG) {
        const float* __restrict__ B = ws + WS_B;
        float ar0 = 0, ai0 = 0, ar1 = 0, ai1 = 0, ar2 = 0, ai2 = 0, ar3 = 0, ai3 = 0;
        for (int a = 0; a < 1024; a += 4) {
            float2 w0 = *(const float2*)&lw[2 * a];
            float2 w1 = *(const float2*)&lw[2 * a + 2];
            float2 w2 = *(const float2*)&lw[2 * a + 4];
            float2 w3 = *(const float2*)&lw[2 * a + 6];
            float2 b0 = *(const float2*)&B[(size_t)(a + 0) * 242 + 2 * t];
            float2 b1 = *(const float2*)&B[(size_t)(a + 1) * 242 + 2 * t];
            float2 b2 = *(const float2*)&B[(size_t)(a + 2) * 242 + 2 * t];
            float2 b3 = *(const float2*)&B[(size_t)(a + 3) * 242 + 2 * t];
            ar0 += w0.x * b0.x - w0.y * b0.y;  ai0 += w0.x * b0.y + w0.y * b0.x;
            ar1 += w1.x * b1.x - w1.y * b1.y;  ai1 += w1.x * b1.y + w1.y * b1.x;
            ar2 += w2.x * b2.x - w2.y * b2.y;  ai2 += w2.x * b2.y + w2.y * b2.x;
            ar3 += w3.x * b3.x - w3.y * b3.y;  ai3 += w3.x * b3.y + w3.y * b3.x;
        }
        float re = (ar0 + ar1) + (ar2 + ar3);
        float im = (ai0 + ai1) + (ai2 + ai3);
        ws[WS_SOUT + r * NANG + t] = (re * re + im * im) * (1.0f / 16777216.0f);
    }
}

// ---------------- K4: scalar loss ----------------
__global__ __launch_bounds__(256) void k_final(const float* __restrict__ ws, float* __restrict__ out)
{
    __shared__ float red[256];
    __shared__ float red2[256];
    __shared__ float dsh[121];
    const int t = threadIdx.x;
    const float* __restrict__ sout = ws + WS_SOUT;
    float tot = 0.0f, band = 0.0f;
    for (int e = t; e < NANG * NANG; e += 256) {
        float v = sout[e];
        int i = e / NANG;
        int j = e - i * NANG;
        tot += v;
        int dd = i - j; if (dd < 0) dd = -dd;
        if (dd <= 5) band += v;
        if (dd == 0) dsh[i] = v;
    }
    red[t] = tot; red2[t] = band;
    __syncthreads();
    for (int s2 = 128; s2 > 0; s2 >>= 1) {
        if (t < s2) { red[t] += red[t + s2]; red2[t] += red2[t + s2]; }
        __syncthreads();
    }
    float total = red[0], bandsum = red2[0];
    __syncthreads();

    float d = 0.0f, y = 0.0f;
    if (t < NANG) {
        d = dsh[t];
        float x = (float)(t - 60);
        float wgt = fmaf(x * x, -0.2f / 3600.0f, 1.0f);
        y = d / wgt;
    }
    red[t] = d; red2[t] = y;
    __syncthreads();
    for (int s2 = 128; s2 > 0; s2 >>= 1) {
        if (t < s2) { red[t] += red[t + s2]; red2[t] += red2[t + s2]; }
        __syncthreads();
    }
    float diag_sum = red[0];
    float mean = red2[0] * (1.0f / 121.0f);
    __syncthreads();

    float dev = (t < NANG) ? (y - mean) : 0.0f;
    red[t] = dev * dev;
    __syncthreads();
    for (int s2 = 128; s2 > 0; s2 >>= 1) {
        if (t < s2) { red[t] += red[t + s2]; }
        __syncthreads();
    }
    if (t == 0) {
        float var = red[0] * (1.0f / 120.0f);   // ddof=1
        float std_ = sqrtf(var);
        float amp = -diag_sum + 0.1f * (total - bandsum);
        out[0] = amp + 200.0f * std_;
    }
}

extern "C" void kernel_launch(void* const* d_in, const int* in_sizes, int n_in,
                              void* d_out, int out_size, void* d_ws, size_t ws_size,
                              hipStream_t stream)
{
    const float* w_re  = (const float*)d_in[0];
    const float* w_im  = (const float*)d_in[1];
    const float* th_re = (const float*)d_in[2];
    const float* th_im = (const float*)d_in[3];
    const float* G_re  = (const float*)d_in[4];
    const float* G_im  = (const float*)d_in[5];
    const float* sv_re = (const float*)d_in[6];
    const float* sv_im = (const float*)d_in[7];
    float* ws  = (float*)d_ws;
    float* out = (float*)d_out;

    k_prep<<<dim3((16384 + 121 * 1024) / 256), 256, 0, stream>>>(w_re, w_im, th_re, th_im, ws);
    k_gemm1<<<dim3(ATILES, KSPLIT), 256, 0, stream>>>(G_re, G_im, sv_re, sv_im, ws);
    k_reduce_part<<<dim3(PART_STRIDE / 256), 256, 0, stream>>>(ws);
    k_gemm2<<<dim3(121), 128, 0, stream>>>(ws);
    k_final<<<dim3(1), 256, 0, stream>>>(ws, out);
}

// Round 2
// 265.381 us; speedup vs baseline: 3.4449x; 3.4449x over previous
//
#include <hip/hip_runtime.h>
#include <math.h>

#define A_NUM 1024
#define L_NUM 16384
#define NANG  121
#define NPAD  256          // cols 0..120 = Re, 128..248 = Im
#define KSPLIT 32          // k-split blocks; l-range per block = 512
#define TA 64              // a-rows per block
#define CHUNK_L 32         // l per LDS chunk
#define CHUNK_K 64         // k per LDS chunk (2*CHUNK_L)
#define ROWP 72            // padded LDS/Bt row length in bf16 elems (144 B)
#define NCHUNK_G 512       // global chunk count = 32768/64

// ws byte offsets
#define WS_TV   0u            // f32 [16384][2]            131072 B
#define WS_WF   131072u       // f32 [121][1024][2]        991232 B
#define WS_BT   1122304u      // bf16 [512][256][72]       18874368 B
#define WS_PART 19996672u     // f32 [32][1024][256]       33554432 B
#define WS_C    53551104u     // f32 [1024][256]           1048576 B
#define WS_SOUT 54599680u     // f32 [121][121]            58564 B

typedef float  f32x4  __attribute__((ext_vector_type(4)));
typedef short  s16x8  __attribute__((ext_vector_type(8)));
typedef unsigned short u16x8 __attribute__((ext_vector_type(8)));
typedef unsigned short u16x4 __attribute__((ext_vector_type(4)));

__device__ __forceinline__ unsigned short f2bf(float x) {
    union { float f; unsigned u; } v; v.f = x;
    unsigned r = v.u + 0x7fffu + ((v.u >> 16) & 1u);   // RNE
    return (unsigned short)(r >> 16);
}

#define GLOAD_LDS16(SRC, DST) \
    __builtin_amdgcn_global_load_lds((const __attribute__((address_space(1))) void*)(SRC), \
                                     (__attribute__((address_space(3))) void*)(DST), 16, 0, 0)

// ---------------- K1: theta_vec + w_full ----------------
__global__ __launch_bounds__(256) void k_prep(
    const float* __restrict__ w_re, const float* __restrict__ w_im,
    const float* __restrict__ th_re, const float* __restrict__ th_im,
    char* __restrict__ wsb)
{
    int idx = blockIdx.x * 256 + threadIdx.x;
    float* tv = (float*)(wsb + WS_TV);
    float* wf = (float*)(wsb + WS_WF);
    if (idx < 16384) {
        int i = idx >> 7, j = idx & 127;
        int r = (i < 64) ? i : 127 - i;
        int c = (j < 64) ? j : 127 - j;
        float tr = th_re[r * 64 + c], ti = th_im[r * 64 + c];
        float inv = rsqrtf(tr * tr + ti * ti);
        tv[2 * idx]     = tr * inv;
        tv[2 * idx + 1] = ti * inv;
    } else if (idx < 16384 + 121 * 1024) {
        int e = idx - 16384;
        int r = e >> 10, a = e & 1023;
        int sr = (r < 61) ? r : 120 - r;
        int sa = (r < 61) ? a : 1023 - a;
        float wr = w_re[sr * 1024 + sa], wi = w_im[sr * 1024 + sa];
        float mag = sqrtf(wr * wr + wi * wi);
        float s = (mag > 1.0f) ? (1.0f / mag) : 1.0f;
        wf[2 * e]     = wr * s;
        wf[2 * e + 1] = wi * s;
    }
}

// ---------------- K1b: build Bt bf16 [512][256][72], chunk-major, padded ----------------
__global__ __launch_bounds__(256) void k_prep_bt(
    const float* __restrict__ sv_re, const float* __restrict__ sv_im,
    char* __restrict__ wsb)
{
    __shared__ float lsr[32][121];
    __shared__ float lsi[32][121];
    const int cg = blockIdx.x;       // 0..511
    const int t  = threadIdx.x;
    const int lbase = cg * 32;
    for (int e = t; e < 32 * 121; e += 256) {
        int l = e / 121, n = e - l * 121;
        lsr[l][n] = sv_re[(size_t)(lbase + l) * 121 + n];
        lsi[l][n] = sv_im[(size_t)(lbase + l) * 121 + n];
    }
    __syncthreads();
    unsigned short* bt = (unsigned short*)(wsb + WS_BT) + (size_t)cg * (NPAD * ROWP);
    #pragma unroll
    for (int i = 0; i < 18; ++i) {
        int o = t + i * 256;             // short4 index < 4608
        int n = o / 18;
        int j = o - n * 18;
        int kl0 = j * 4;
        u16x4 val;
        #pragma unroll
        for (int q = 0; q < 4; ++q) {
            int kl = kl0 + q;
            float v = 0.0f;
            if (kl < 64) {
                int lloc = kl >> 1;
                if (n < 121)                     v = (kl & 1) ? -lsi[lloc][n] : lsr[lloc][n];
                else if (n >= 128 && n < 249)    { int m = n - 128; v = (kl & 1) ? lsr[lloc][m] : lsi[lloc][m]; }
            }
            val[q] = f2bf(v);
        }
        *(u16x4*)&bt[(size_t)o * 4] = val;
    }
}

// ---------------- K2: MFMA GEMM  partial[k][a][n] = A(Gtheta) @ Bt ----------------
// grid 512: bid = kidx + 32*atile  (same kidx -> same XCD for Bt L2 reuse)
// block 256 thr = 4 waves, wave tile 64a x 64n
__global__ __launch_bounds__(256, 2) void k_gemm1(
    const float* __restrict__ G_re, const float* __restrict__ G_im,
    char* __restrict__ wsb)
{
    __shared__ __align__(16) unsigned short lA[TA * ROWP];     // 9216 B
    __shared__ __align__(16) unsigned short lB[NPAD * ROWP];   // 36864 B

    const int t = threadIdx.x;
    const int bid = blockIdx.x;
    const int kidx  = bid & 31;
    const int atile = bid >> 5;
    const int a0 = atile * TA;
    const int l_begin = kidx * 512;

    const float* __restrict__ tvF = (const float*)(wsb + WS_TV);
    const unsigned short* __restrict__ BtG = (const unsigned short*)(wsb + WS_BT);

    const int wid = t >> 6, lane = t & 63;
    const int arow = lane & 15;
    const int koff = (lane >> 4) * 8;

    const int arow_s = t >> 3;     // A-stage row within 32
    const int slot   = t & 7;
    const int lloc   = slot * 4;

    f32x4 acc[4][4];
    #pragma unroll
    for (int j = 0; j < 4; ++j)
        #pragma unroll
        for (int s = 0; s < 4; ++s) acc[j][s] = (f32x4)(0.0f);

    for (int c = 0; c < 16; ++c) {
        const int l0 = l_begin + c * CHUNK_L;
        // ---- stage A: Gtheta -> bf16 LDS [64][72]
        #pragma unroll
        for (int p = 0; p < 2; ++p) {
            const int a = p * 32 + arow_s;
            const float* grp = G_re + (size_t)(a0 + a) * L_NUM + l0 + lloc;
            const float* gip = G_im + (size_t)(a0 + a) * L_NUM + l0 + lloc;
            float4 gr = *(const float4*)grp;
            float4 gi = *(const float4*)gip;
            const float* tvp = tvF + 2 * (l0 + lloc);
            float4 t0 = *(const float4*)tvp;
            float4 t1 = *(const float4*)(tvp + 4);
            u16x8 pk;
            pk[0] = f2bf(gr.x * t0.x - gi.x * t0.y); pk[1] = f2bf(gr.x * t0.y + gi.x * t0.x);
            pk[2] = f2bf(gr.y * t0.z - gi.y * t0.w); pk[3] = f2bf(gr.y * t0.w + gi.y * t0.z);
            pk[4] = f2bf(gr.z * t1.x - gi.z * t1.y); pk[5] = f2bf(gr.z * t1.y + gi.z * t1.x);
            pk[6] = f2bf(gr.w * t1.z - gi.w * t1.w); pk[7] = f2bf(gr.w * t1.w + gi.w * t1.z);
            *(u16x8*)&lA[a * ROWP + slot * 8] = pk;
        }
        // ---- stage B: global_load_lds 16B x9, fully linear (Bt pre-transposed+padded)
        {
            const int cgk = kidx * 16 + c;
            const unsigned short* bsrc = BtG + (size_t)cgk * (NPAD * ROWP);
            unsigned short* ldsb = lB + (size_t)(t & ~63) * 8;
            const unsigned short* gsrc = bsrc + (size_t)t * 8;
            #pragma unroll
            for (int i = 0; i < 9; ++i) {
                GLOAD_LDS16(gsrc + (size_t)i * 2048, ldsb + (size_t)i * 2048);
            }
        }
        __syncthreads();
        // ---- MFMA
        #pragma unroll
        for (int kh = 0; kh < 2; ++kh) {
            s16x8 af[4], bf[4];
            #pragma unroll
            for (int j = 0; j < 4; ++j)
                af[j] = *(const s16x8*)&lA[(j * 16 + arow) * ROWP + kh * 32 + koff];
            #pragma unroll
            for (int s = 0; s < 4; ++s)
                bf[s] = *(const s16x8*)&lB[(wid * 64 + s * 16 + arow) * ROWP + kh * 32 + koff];
            #pragma unroll
            for (int j = 0; j < 4; ++j)
                #pragma unroll
                for (int s = 0; s < 4; ++s)
                    acc[j][s] = __builtin_amdgcn_mfma_f32_16x16x32_bf16(af[j], bf[s], acc[j][s], 0, 0, 0);
        }
        __syncthreads();
    }

    // ---- write partial [a][n] f32
    float* part = (float*)(wsb + WS_PART) + (size_t)kidx * (A_NUM * NPAD);
    #pragma unroll
    for (int j = 0; j < 4; ++j) {
        #pragma unroll
        for (int s = 0; s < 4; ++s) {
            const int col  = wid * 64 + s * 16 + (lane & 15);
            const int rowb = a0 + j * 16 + (lane >> 4) * 4;
            f32x4 v = acc[j][s];
            #pragma unroll
            for (int r = 0; r < 4; ++r)
                part[(size_t)(rowb + r) * NPAD + col] = v[r];
        }
    }
}

// ---------------- K2b: C = sum of 32 partials ----------------
__global__ __launch_bounds__(256) void k_reduce_part(char* __restrict__ wsb)
{
    const int e = blockIdx.x * 256 + threadIdx.x;   // < 262144
    const float* part = (const float*)(wsb + WS_PART);
    float s = 0.0f;
    #pragma unroll
    for (int p = 0; p < KSPLIT; ++p) s += part[(size_t)p * (A_NUM * NPAD) + e];
    ((float*)(wsb + WS_C))[e] = s;
}

// ---------------- K3: sout = |w_full @ C|^2 / (A*L) ----------------
__global__ __launch_bounds__(128) void k_gemm2(char* __restrict__ wsb)
{
    __shared__ float lw[2048];
    const int r = blockIdx.x;
    const int t = threadIdx.x;
    const float* wf = (const float*)(wsb + WS_WF) + r * 2048;
    #pragma unroll
    for (int k = 0; k < 16; ++k) lw[t + k * 128] = wf[t + k * 128];
    __syncthreads();
    if (t < 121) {
        const float* __restrict__ C = (const float*)(wsb + WS_C);
        float re = 0.0f, im = 0.0f;
        for (int a = 0; a < 1024; a += 8) {
            #pragma unroll
            for (int u = 0; u < 8; ++u) {
                float wr = lw[2 * (a + u)], wi = lw[2 * (a + u) + 1];
                float br = C[(size_t)(a + u) * NPAD + t];
                float bi = C[(size_t)(a + u) * NPAD + 128 + t];
                re += wr * br - wi * bi;
                im += wr * bi + wi * br;
            }
        }
        ((float*)(wsb + WS_SOUT))[r * 121 + t] = (re * re + im * im) * (1.0f / 16777216.0f);
    }
}

// ---------------- K4: scalar loss ----------------
__global__ __launch_bounds__(256) void k_final(const char* __restrict__ wsb, float* __restrict__ out)
{
    __shared__ float red[256];
    __shared__ float red2[256];
    __shared__ float dsh[121];
    const int t = threadIdx.x;
    const float* __restrict__ sout = (const float*)(wsb + WS_SOUT);
    float tot = 0.0f, band = 0.0f;
    for (int e = t; e < NANG * NANG; e += 256) {
        float v = sout[e];
        int i = e / NANG;
        int j = e - i * NANG;
        tot += v;
        int dd = i - j; if (dd < 0) dd = -dd;
        if (dd <= 5) band += v;
        if (dd == 0) dsh[i] = v;
    }
    red[t] = tot; red2[t] = band;
    __syncthreads();
    for (int s2 = 128; s2 > 0; s2 >>= 1) {
        if (t < s2) { red[t] += red[t + s2]; red2[t] += red2[t + s2]; }
        __syncthreads();
    }
    float total = red[0], bandsum = red2[0];
    __syncthreads();

    float d = 0.0f, y = 0.0f;
    if (t < NANG) {
        d = dsh[t];
        float x = (float)(t - 60);
        float wgt = fmaf(x * x, -0.2f / 3600.0f, 1.0f);
        y = d / wgt;
    }
    red[t] = d; red2[t] = y;
    __syncthreads();
    for (int s2 = 128; s2 > 0; s2 >>= 1) {
        if (t < s2) { red[t] += red[t + s2]; red2[t] += red2[t + s2]; }
        __syncthreads();
    }
    float diag_sum = red[0];
    float mean = red2[0] * (1.0f / 121.0f);
    __syncthreads();

    float dev = (t < NANG) ? (y - mean) : 0.0f;
    red[t] = dev * dev;
    __syncthreads();
    for (int s2 = 128; s2 > 0; s2 >>= 1) {
        if (t < s2) { red[t] += red[t + s2]; }
        __syncthreads();
    }
    if (t == 0) {
        float var = red[0] * (1.0f / 120.0f);   // ddof=1
        float std_ = sqrtf(var);
        float amp = -diag_sum + 0.1f * (total - bandsum);
        out[0] = amp + 200.0f * std_;
    }
}

extern "C" void kernel_launch(void* const* d_in, const int* in_sizes, int n_in,
                              void* d_out, int out_size, void* d_ws, size_t ws_size,
                              hipStream_t stream)
{
    const float* w_re  = (const float*)d_in[0];
    const float* w_im  = (const float*)d_in[1];
    const float* th_re = (const float*)d_in[2];
    const float* th_im = (const float*)d_in[3];
    const float* G_re  = (const float*)d_in[4];
    const float* G_im  = (const float*)d_in[5];
    const float* sv_re = (const float*)d_in[6];
    const float* sv_im = (const float*)d_in[7];
    char* wsb  = (char*)d_ws;
    float* out = (float*)d_out;

    k_prep<<<dim3(548), 256, 0, stream>>>(w_re, w_im, th_re, th_im, wsb);
    k_prep_bt<<<dim3(NCHUNK_G), 256, 0, stream>>>(sv_re, sv_im, wsb);
    k_gemm1<<<dim3(512), 256, 0, stream>>>(G_re, G_im, wsb);
    k_reduce_part<<<dim3(1024), 256, 0, stream>>>(wsb);
    k_gemm2<<<dim3(121), 128, 0, stream>>>(wsb);
    k_final<<<dim3(1), 256, 0, stream>>>(wsb, out);
}

// Round 3
// 240.641 us; speedup vs baseline: 3.7990x; 1.1028x over previous
//
#include <hip/hip_runtime.h>
#include <math.h>

#define A_NUM 1024
#define L_NUM 16384
#define NANG  121
#define NPAD  256          // cols 0..120 = Re, 128..248 = Im
#define KSPLIT 32          // k-split; l-range per block = 512
#define TA 128             // a-rows per block
#define NCH 16             // chunks per block (32 l each)
#define ROWP 72            // padded row length in bf16 elems (144 B)

// ws byte offsets (identical layout to round 2)
#define WS_TV   0u            // f32 [16384][2]
#define WS_WF   131072u       // f32 [121][1024][2]
#define WS_BT   1122304u      // bf16 [512][256][72]
#define WS_PART 19996672u     // f32 [32][1024][256]
#define WS_C    53551104u     // f32 [1024][256]
#define WS_SOUT 54599680u     // f32 [121][121]

typedef unsigned short ushort_t;
typedef float  f32x4  __attribute__((ext_vector_type(4)));
typedef short  s16x8  __attribute__((ext_vector_type(8)));
typedef unsigned short u16x8 __attribute__((ext_vector_type(8)));

__device__ __forceinline__ unsigned short f2bf(float x) {
    union { float f; unsigned u; } v; v.f = x;
    unsigned r = v.u + 0x7fffu + ((v.u >> 16) & 1u);   // RNE
    return (unsigned short)(r >> 16);
}

#define GLOAD_LDS16(SRC, DST) \
    __builtin_amdgcn_global_load_lds((const __attribute__((address_space(1))) void*)(SRC), \
                                     (__attribute__((address_space(3))) void*)(DST), 16, 0, 0)

// ---------------- K1: theta_vec + w_full ----------------
__global__ __launch_bounds__(256) void k_prep(
    const float* __restrict__ w_re, const float* __restrict__ w_im,
    const float* __restrict__ th_re, const float* __restrict__ th_im,
    char* __restrict__ wsb)
{
    int idx = blockIdx.x * 256 + threadIdx.x;
    float* tv = (float*)(wsb + WS_TV);
    float* wf = (float*)(wsb + WS_WF);
    if (idx < 16384) {
        int i = idx >> 7, j = idx & 127;
        int r = (i < 64) ? i : 127 - i;
        int c = (j < 64) ? j : 127 - j;
        float tr = th_re[r * 64 + c], ti = th_im[r * 64 + c];
        float inv = rsqrtf(tr * tr + ti * ti);
        tv[2 * idx]     = tr * inv;
        tv[2 * idx + 1] = ti * inv;
    } else if (idx < 16384 + 121 * 1024) {
        int e = idx - 16384;
        int r = e >> 10, a = e & 1023;
        int sr = (r < 61) ? r : 120 - r;
        int sa = (r < 61) ? a : 1023 - a;
        float wr = w_re[sr * 1024 + sa], wi = w_im[sr * 1024 + sa];
        float mag = sqrtf(wr * wr + wi * wi);
        float s = (mag > 1.0f) ? (1.0f / mag) : 1.0f;
        wf[2 * e]     = wr * s;
        wf[2 * e + 1] = wi * s;
    }
}

// ---------------- K1b: build Bt bf16 [512 chunks][256 rows][72] ----------------
__global__ __launch_bounds__(256) void k_prep_bt(
    const float* __restrict__ sv_re, const float* __restrict__ sv_im,
    char* __restrict__ wsb)
{
    __shared__ float lsr[32][128];
    __shared__ float lsi[32][128];
    const int cg = blockIdx.x;       // 0..511
    const int t  = threadIdx.x;
    const int lbase = cg * 32;
    for (int e = t; e < 4096; e += 256) {
        int l = e >> 7, n = e & 127;
        float vr = 0.0f, vi = 0.0f;
        if (n < 121) {
            vr = sv_re[(size_t)(lbase + l) * 121 + n];
            vi = sv_im[(size_t)(lbase + l) * 121 + n];
        }
        lsr[l][n] = vr; lsi[l][n] = vi;
    }
    __syncthreads();
    ushort_t* bt = (ushort_t*)(wsb + WS_BT) + (size_t)cg * (NPAD * ROWP);
    const int m = t - 128;
    #pragma unroll
    for (int kk = 0; kk < 9; ++kk) {
        u16x8 v;
        #pragma unroll
        for (int qq = 0; qq < 8; ++qq) {
            int k = kk * 8 + qq;
            float x = 0.0f;
            if (k < 64) {
                int l = k >> 1;
                if (t < 121)                       x = (k & 1) ? -lsi[l][t] : lsr[l][t];
                else if (t >= 128 && t < 249)      x = (k & 1) ?  lsr[l][m] : lsi[l][m];
            }
            v[qq] = f2bf(x);
        }
        *(u16x8*)&bt[(size_t)t * ROWP + kk * 8] = v;
    }
}

// ---------------- K2: pipelined MFMA GEMM ----------------
struct APf { float4 gr0, gr1, gi0, gi1; };

__device__ __forceinline__ APf a_issue(const float* __restrict__ G_re, const float* __restrict__ G_im,
                                       size_t rowbase, int loff) {
    APf p;
    const float* grp = G_re + rowbase + loff;
    const float* gip = G_im + rowbase + loff;
    p.gr0 = *(const float4*)grp;       p.gr1 = *(const float4*)(grp + 4);
    p.gi0 = *(const float4*)gip;       p.gi1 = *(const float4*)(gip + 4);
    return p;
}

__device__ __forceinline__ void a_store(const APf& p, const float* __restrict__ ltv,
                                        ushort_t* __restrict__ lAb, int c, int arow, int aslot) {
    const float* tp = ltv + c * 64 + aslot * 16;
    float4 t0 = *(const float4*)tp;
    float4 t1 = *(const float4*)(tp + 4);
    float4 t2 = *(const float4*)(tp + 8);
    float4 t3 = *(const float4*)(tp + 12);
    u16x8 k0, k1;
    k0[0] = f2bf(p.gr0.x * t0.x - p.gi0.x * t0.y);  k0[1] = f2bf(p.gr0.x * t0.y + p.gi0.x * t0.x);
    k0[2] = f2bf(p.gr0.y * t0.z - p.gi0.y * t0.w);  k0[3] = f2bf(p.gr0.y * t0.w + p.gi0.y * t0.z);
    k0[4] = f2bf(p.gr0.z * t1.x - p.gi0.z * t1.y);  k0[5] = f2bf(p.gr0.z * t1.y + p.gi0.z * t1.x);
    k0[6] = f2bf(p.gr0.w * t1.z - p.gi0.w * t1.w);  k0[7] = f2bf(p.gr0.w * t1.w + p.gi0.w * t1.z);
    k1[0] = f2bf(p.gr1.x * t2.x - p.gi1.x * t2.y);  k1[1] = f2bf(p.gr1.x * t2.y + p.gi1.x * t2.x);
    k1[2] = f2bf(p.gr1.y * t2.z - p.gi1.y * t2.w);  k1[3] = f2bf(p.gr1.y * t2.w + p.gi1.y * t2.z);
    k1[4] = f2bf(p.gr1.z * t3.x - p.gi1.z * t3.y);  k1[5] = f2bf(p.gr1.z * t3.y + p.gi1.z * t3.x);
    k1[6] = f2bf(p.gr1.w * t3.z - p.gi1.w * t3.w);  k1[7] = f2bf(p.gr1.w * t3.w + p.gi1.w * t3.z);
    *(u16x8*)&lAb[arow * ROWP + aslot * 16]     = k0;
    *(u16x8*)&lAb[arow * ROWP + aslot * 16 + 8] = k1;
}

__device__ __forceinline__ void b_issue(const ushort_t* __restrict__ bsrc,
                                        ushort_t* __restrict__ lBb, int w, int lane) {
    #pragma unroll
    for (int i = 0; i < 5; ++i) {
        int seg = w + 8 * i;                 // 36 segments of 1024 B
        if (seg < 36)
            GLOAD_LDS16(bsrc + seg * 512 + lane * 8, lBb + seg * 512);
    }
}

__device__ __forceinline__ void do_mfma(const ushort_t* __restrict__ lAb, const ushort_t* __restrict__ lBb,
                                        f32x4 (&acc)[4][4], int wa, int wn, int lane) {
    const int fr = lane & 15;
    const int fk = (lane >> 4) * 8;
    #pragma unroll
    for (int kh = 0; kh < 2; ++kh) {
        s16x8 af[4], bf[4];
        #pragma unroll
        for (int j = 0; j < 4; ++j)
            af[j] = *(const s16x8*)&lAb[(wa * 64 + j * 16 + fr) * ROWP + kh * 32 + fk];
        #pragma unroll
        for (int s = 0; s < 4; ++s)
            bf[s] = *(const s16x8*)&lBb[(wn * 64 + s * 16 + fr) * ROWP + kh * 32 + fk];
        #pragma unroll
        for (int j = 0; j < 4; ++j)
            #pragma unroll
            for (int s = 0; s < 4; ++s)
                acc[j][s] = __builtin_amdgcn_mfma_f32_16x16x32_bf16(af[j], bf[s], acc[j][s], 0, 0, 0);
    }
}

__global__ __launch_bounds__(512, 2) void k_gemm1(
    const float* __restrict__ G_re, const float* __restrict__ G_im,
    char* __restrict__ wsb)
{
    __shared__ __align__(16) ushort_t lA[2][TA * ROWP];     // 2 x 18432 B
    __shared__ __align__(16) ushort_t lB[2][NPAD * ROWP];   // 2 x 36864 B
    __shared__ __align__(16) float ltv[1024];               // 4 KB

    const int t = threadIdx.x;
    const int lane = t & 63, w = t >> 6;
    const int kidx  = blockIdx.x & 31;
    const int atile = blockIdx.x >> 5;
    const int a0 = atile * TA;
    const int l_begin = kidx * 512;

    const float* __restrict__ tvF = (const float*)(wsb + WS_TV);
    const ushort_t* __restrict__ BtG = (const ushort_t*)(wsb + WS_BT);

    // preload theta slice for this block's l-range
    *(float2*)&ltv[2 * t] = *(const float2*)&tvF[2 * l_begin + 2 * t];

    const int arow = t >> 2, aslot = t & 3;   // A-stage: 128 rows x 4 slots (8 complex l each)
    const size_t rowbase = (size_t)(a0 + arow) * L_NUM + l_begin;
    const int wa = w & 1, wn = w >> 1;        // wave tile 64a x 64n

    f32x4 acc[4][4];
    #pragma unroll
    for (int j = 0; j < 4; ++j)
        #pragma unroll
        for (int s = 0; s < 4; ++s) acc[j][s] = (f32x4)(0.0f);

    // prologue: chunk 0
    APf p0 = a_issue(G_re, G_im, rowbase, aslot * 8);
    b_issue(BtG + (size_t)(kidx * 16) * (NPAD * ROWP), lB[0], w, lane);
    __syncthreads();                       // ltv visible (+ drains)
    a_store(p0, ltv, lA[0], 0, arow, aslot);
    __syncthreads();                       // A0/B0 ready

    for (int c = 0; c < NCH; ++c) {
        const int cur = c & 1;
        if (c + 1 < NCH) {
            APf pn = a_issue(G_re, G_im, rowbase, (c + 1) * 32 + aslot * 8);
            b_issue(BtG + (size_t)(kidx * 16 + c + 1) * (NPAD * ROWP), lB[cur ^ 1], w, lane);
            do_mfma(lA[cur], lB[cur], acc, wa, wn, lane);
            a_store(pn, ltv, lA[cur ^ 1], c + 1, arow, aslot);
            __syncthreads();
        } else {
            do_mfma(lA[cur], lB[cur], acc, wa, wn, lane);
        }
    }

    // write partial [a][n] f32
    float* part = (float*)(wsb + WS_PART) + (size_t)kidx * (A_NUM * NPAD);
    const int fr = lane & 15, fq = lane >> 4;
    #pragma unroll
    for (int j = 0; j < 4; ++j) {
        #pragma unroll
        for (int s = 0; s < 4; ++s) {
            const int col  = wn * 64 + s * 16 + fr;
            const int rowb = a0 + wa * 64 + j * 16 + fq * 4;
            f32x4 v = acc[j][s];
            #pragma unroll
            for (int r = 0; r < 4; ++r)
                part[(size_t)(rowb + r) * NPAD + col] = v[r];
        }
    }
}

// ---------------- K2b: C = sum of 32 partials (float4) ----------------
__global__ __launch_bounds__(256) void k_reduce_part(char* __restrict__ wsb)
{
    const int e4 = blockIdx.x * 256 + threadIdx.x;   // float4 index < 65536
    const f32x4* part = (const f32x4*)(wsb + WS_PART);
    f32x4 s = part[e4];
    #pragma unroll
    for (int p = 1; p < KSPLIT; ++p) s += part[(size_t)p * 65536 + e4];
    ((f32x4*)(wsb + WS_C))[e4] = s;
}

// ---------------- K3: sout = |w_full @ C|^2 / (A*L) ----------------
__global__ __launch_bounds__(512) void k_gemm2(char* __restrict__ wsb)
{
    __shared__ float lw[2048];
    __shared__ float rre[4][128];
    __shared__ float rim[4][128];
    const int r = blockIdx.x;
    const int t = threadIdx.x;
    const float* wf = (const float*)(wsb + WS_WF) + r * 2048;
    *(float4*)&lw[4 * t] = *(const float4*)&wf[4 * t];
    __syncthreads();
    const int q = t >> 7, n = t & 127;
    const float* __restrict__ C = (const float*)(wsb + WS_C);
    const float* __restrict__ Cb = C + (size_t)q * 256 * 256 + n;
    const float* __restrict__ lwb = lw + q * 512;
    float re = 0.0f, im = 0.0f;
    for (int a8 = 0; a8 < 256; a8 += 8) {
        #pragma unroll
        for (int u = 0; u < 8; ++u) {
            float wr = lwb[2 * (a8 + u)], wi = lwb[2 * (a8 + u) + 1];
            float br = Cb[(size_t)(a8 + u) * 256];
            float bi = Cb[(size_t)(a8 + u) * 256 + 128];
            re += wr * br - wi * bi;
            im += wr * bi + wi * br;
        }
    }
    rre[q][n] = re; rim[q][n] = im;
    __syncthreads();
    if (t < 121) {
        float rr = rre[0][t] + rre[1][t] + rre[2][t] + rre[3][t];
        float ii = rim[0][t] + rim[1][t] + rim[2][t] + rim[3][t];
        ((float*)(wsb + WS_SOUT))[r * 121 + t] = (rr * rr + ii * ii) * (1.0f / 16777216.0f);
    }
}

// ---------------- K4: scalar loss ----------------
__global__ __launch_bounds__(256) void k_final(const char* __restrict__ wsb, float* __restrict__ out)
{
    __shared__ float red[256];
    __shared__ float red2[256];
    __shared__ float dsh[121];
    const int t = threadIdx.x;
    const float* __restrict__ sout = (const float*)(wsb + WS_SOUT);
    float tot = 0.0f, band = 0.0f;
    for (int e = t; e < NANG * NANG; e += 256) {
        float v = sout[e];
        int i = e / NANG;
        int j = e - i * NANG;
        tot += v;
        int dd = i - j; if (dd < 0) dd = -dd;
        if (dd <= 5) band += v;
        if (dd == 0) dsh[i] = v;
    }
    red[t] = tot; red2[t] = band;
    __syncthreads();
    for (int s2 = 128; s2 > 0; s2 >>= 1) {
        if (t < s2) { red[t] += red[t + s2]; red2[t] += red2[t + s2]; }
        __syncthreads();
    }
    float total = red[0], bandsum = red2[0];
    __syncthreads();

    float d = 0.0f, y = 0.0f;
    if (t < NANG) {
        d = dsh[t];
        float x = (float)(t - 60);
        float wgt = fmaf(x * x, -0.2f / 3600.0f, 1.0f);
        y = d / wgt;
    }
    red[t] = d; red2[t] = y;
    __syncthreads();
    for (int s2 = 128; s2 > 0; s2 >>= 1) {
        if (t < s2) { red[t] += red[t + s2]; red2[t] += red2[t + s2]; }
        __syncthreads();
    }
    float diag_sum = red[0];
    float mean = red2[0] * (1.0f / 121.0f);
    __syncthreads();

    float dev = (t < NANG) ? (y - mean) : 0.0f;
    red[t] = dev * dev;
    __syncthreads();
    for (int s2 = 128; s2 > 0; s2 >>= 1) {
        if (t < s2) { red[t] += red[t + s2]; }
        __syncthreads();
    }
    if (t == 0) {
        float var = red[0] * (1.0f / 120.0f);   // ddof=1
        float std_ = sqrtf(var);
        float amp = -diag_sum + 0.1f * (total - bandsum);
        out[0] = amp + 200.0f * std_;
    }
}

extern "C" void kernel_launch(void* const* d_in, const int* in_sizes, int n_in,
                              void* d_out, int out_size, void* d_ws, size_t ws_size,
                              hipStream_t stream)
{
    const float* w_re  = (const float*)d_in[0];
    const float* w_im  = (const float*)d_in[1];
    const float* th_re = (const float*)d_in[2];
    const float* th_im = (const float*)d_in[3];
    const float* G_re  = (const float*)d_in[4];
    const float* G_im  = (const float*)d_in[5];
    const float* sv_re = (const float*)d_in[6];
    const float* sv_im = (const float*)d_in[7];
    char* wsb  = (char*)d_ws;
    float* out = (float*)d_out;

    k_prep<<<dim3(548), 256, 0, stream>>>(w_re, w_im, th_re, th_im, wsb);
    k_prep_bt<<<dim3(512), 256, 0, stream>>>(sv_re, sv_im, wsb);
    k_gemm1<<<dim3(256), 512, 0, stream>>>(G_re, G_im, wsb);
    k_reduce_part<<<dim3(256), 256, 0, stream>>>(wsb);
    k_gemm2<<<dim3(121), 512, 0, stream>>>(wsb);
    k_final<<<dim3(1), 256, 0, stream>>>(wsb, out);
}